// Round 7
// baseline (375.313 us; speedup 1.0000x reference)
//
#include <hip/hip_runtime.h>
#include <hip/hip_bf16.h>
#include <math.h>

// TriangleAttention — round 7: LN hoisted out; ka reads zn frags from global.
// B=2, L=256, D=64, H=4, Dh=16.
// kln: LN once -> zn bf16 [bl*256+pos][64] in ws.
// ka:  grid 2048=(bl,h); S^T formulation (round 6), zn frags direct from global,
//      LDS = KSH(12KB,stride24) + VT(8.25KB) + per-wave scratch(1.25KB x4) ~ 25KB
//      -> 5 blocks/CU. One barrier.
// k3:  out = sum_h GO_h @ Wo_h^T + bo.
//
// mfma_f32_16x16x32_bf16 layouts (verified rounds 2-6):
//   A[m = lane&15][k = quad*8 + u]
//   B[k = quad*8 + u][n = lane&15]
//   C/D: col = lane&15, row = quad*4 + reg

typedef __attribute__((ext_vector_type(4))) float f32x4;
typedef __attribute__((ext_vector_type(8))) short s16x8;

#define MFMA16(a, b, c) __builtin_amdgcn_mfma_f32_16x16x32_bf16((a), (b), (c), 0, 0, 0)

__device__ __forceinline__ unsigned pk2(float a, float b) {   // 2xf32 -> packed bf16x2 (RNE)
    union { __hip_bfloat162 h; unsigned u; } c;
    float2 t; t.x = a; t.y = b;
    c.h = __float22bfloat162_rn(t);
    return c.u;
}
__device__ __forceinline__ s16x8 cvt8(const float* p) {  // 8 fp32 -> bf16x8
    union { unsigned u[4]; s16x8 v; } r;
    r.u[0] = pk2(p[0], p[1]); r.u[1] = pk2(p[2], p[3]);
    r.u[2] = pk2(p[4], p[5]); r.u[3] = pk2(p[6], p[7]);
    return r.v;
}

// ws layout (shorts)
static constexpr size_t ZNOFF = 0;                        // zn bf16 [131072 rows][64]
static constexpr size_t GOOFF = (size_t)512 * 256 * 64;   // GO [h][bl][pos][16]

// ---------------------------------------------------------------- LN kernel
__global__ __launch_bounds__(256, 2)
void kln(const float* __restrict__ z, const float* __restrict__ ln_s,
         const float* __restrict__ ln_b, short* __restrict__ ws)
{
    const int tid = threadIdx.x, bl = blockIdx.x;
    const size_t row = (size_t)bl * 256 + tid;
    float zn[64];
    const float4* zp4 = (const float4*)(z + row * 64);
    #pragma unroll
    for (int gq = 0; gq < 16; ++gq) {
        float4 v4 = zp4[gq];
        zn[gq * 4 + 0] = v4.x; zn[gq * 4 + 1] = v4.y;
        zn[gq * 4 + 2] = v4.z; zn[gq * 4 + 3] = v4.w;
    }
    float mu = 0.f;
    #pragma unroll
    for (int k = 0; k < 64; ++k) mu += zn[k];
    mu *= (1.f / 64.f);
    float va = 0.f;
    #pragma unroll
    for (int k = 0; k < 64; ++k) { float d = zn[k] - mu; va += d * d; }
    const float rs = rsqrtf(va * (1.f / 64.f) + 1e-5f);
    #pragma unroll
    for (int k = 0; k < 64; ++k) zn[k] = (zn[k] - mu) * rs * ln_s[k] + ln_b[k];
    short* dst = ws + ZNOFF + row * 64;
    #pragma unroll
    for (int gq = 0; gq < 8; ++gq) {
        union { unsigned u[4]; s16x8 v; } pkv;
        pkv.u[0] = pk2(zn[gq * 8 + 0], zn[gq * 8 + 1]);
        pkv.u[1] = pk2(zn[gq * 8 + 2], zn[gq * 8 + 3]);
        pkv.u[2] = pk2(zn[gq * 8 + 4], zn[gq * 8 + 5]);
        pkv.u[3] = pk2(zn[gq * 8 + 6], zn[gq * 8 + 7]);
        *(s16x8*)&dst[gq * 8] = pkv.v;
    }
}

// ---------------------------------------------------------------- fused attention
// LDS map (shorts): KSH [256 pos][24-stride, dh in first 16]; VT [16 dh][264];
// SCR per-wave 640 sh: QT tile [pos16][16] then P [i16][40-stride].
static constexpr int KSH = 0;            // 6144 sh
static constexpr int VT  = 6144;         // 4224 sh
static constexpr int SCR = 10368;        // 4 x 640 sh
static constexpr int LDS_EL = 12928;     // 25856 B -> 5(6) blocks/CU

__global__ __launch_bounds__(256, 5)
void ka_fused(const short* __restrict__ zng, const float* __restrict__ Wq,
              const float* __restrict__ Wk, const float* __restrict__ Wv,
              const float* __restrict__ Wg, const float* __restrict__ bg,
              short* __restrict__ go)
{
    __shared__ __align__(16) short lds[LDS_EL];
    const int tid = threadIdx.x, lane = tid & 63, w = tid >> 6;
    const int n16 = lane & 15, quad = lane >> 4;
    const bool qlo = (quad < 2);
    const int g = blockIdx.x, bl = g >> 2, h = g & 3;
    short* scr = &lds[SCR + w * 640];

    // ---- zn fragments direct from global (coalesced b128) ----
    s16x8 zf[4][2];
    const short* zb = zng + ((size_t)bl * 256 + w * 64 + n16) * 64;
    #pragma unroll
    for (int t = 0; t < 4; ++t) {
        zf[t][0] = *(const s16x8*)&zb[t * 1024 + quad * 8];
        zf[t][1] = *(const s16x8*)&zb[t * 1024 + 32 + quad * 8];
    }

    // ---- W head-slice frags ----
    s16x8 bq[2], bk[2], bv[2], bgf[2];
    #pragma unroll
    for (int ks = 0; ks < 2; ++ks) {
        size_t off = (size_t)(h * 16 + n16) * 64 + ks * 32 + quad * 8;
        bq[ks] = cvt8(Wq + off);  bk[ks] = cvt8(Wk + off);
        bv[ks] = cvt8(Wv + off);  bgf[ks] = cvt8(Wg + off);
    }
    const float4 bg4 = *(const float4*)(bg + h * 16 + quad * 4);
    constexpr float QS = 0.25f * 1.44269504088896340736f;   // 1/sqrt(Dh) * log2(e)

    // ---- projections; Q^T via tiny wave-private LDS transpose ----
    float g4t[4][4];
    s16x8 qa[4];
    #pragma unroll
    for (int t = 0; t < 4; ++t) {
        f32x4 aq = {}, ak = {}, av = {}, ag = {};
        aq = MFMA16(bq[0],  zf[t][0], aq); aq = MFMA16(bq[1],  zf[t][1], aq);  // Q^T
        ak = MFMA16(bk[0],  zf[t][0], ak); ak = MFMA16(bk[1],  zf[t][1], ak);  // K^T
        ag = MFMA16(bgf[0], zf[t][0], ag); ag = MFMA16(bgf[1], zf[t][1], ag);  // G^T
        av = MFMA16(zf[t][0], bv[0], av);  av = MFMA16(zf[t][1], bv[1], av);   // V
        {   // Q^T -> scr QT [pos16][16] (scaled), then read back as B-frag
            uint2 p = {pk2(aq[0] * QS, aq[1] * QS), pk2(aq[2] * QS, aq[3] * QS)};
            *(uint2*)&scr[n16 * 16 + quad * 4] = p;
        }
        {   // K^T -> KSH[pos][dh], stride 24
            uint2 p = {pk2(ak[0], ak[1]), pk2(ak[2], ak[3])};
            *(uint2*)&lds[KSH + (w * 64 + t * 16 + n16) * 24 + quad * 4] = p;
        }
        {   // V -> VT[dh][pos]
            uint2 p = {pk2(av[0], av[1]), pk2(av[2], av[3])};
            *(uint2*)&lds[VT + n16 * 264 + (w * 64 + t * 16 + quad * 4)] = p;
        }
        #pragma unroll
        for (int r = 0; r < 4; ++r)
            g4t[t][r] = 1.f / (1.f + __expf(-(ag[r] + bg4[r])));
        // Q^T B-frag (wave-private, in-order DS; quads 2,3 zero: Dh=16 < K=32)
        s16x8 q = {};
        if (qlo) q = *(const s16x8*)&scr[n16 * 16 + quad * 8];
        qa[t] = q;
    }
    __syncthreads();   // the ONLY barrier: KSH/VT visible

    // ---- attention: S^T = K@Q^T; P packed [i][j] in scr; O^T = V^T@P^T ----
    float lrow[4][4];
    f32x4 o4[4];
    #pragma unroll
    for (int qt = 0; qt < 4; ++qt) {
        o4[qt] = {};
        #pragma unroll
        for (int r = 0; r < 4; ++r) lrow[qt][r] = 0.f;
    }
    for (int ch = 0; ch < 8; ++ch) {                 // 32 keys per chunk
        s16x8 kf0 = {}, kf1 = {};
        if (qlo) {
            kf0 = *(const s16x8*)&lds[KSH + ((ch * 2 + 0) * 16 + n16) * 24 + quad * 8];
            kf1 = *(const s16x8*)&lds[KSH + ((ch * 2 + 1) * 16 + n16) * 24 + quad * 8];
        }
        s16x8 vf = *(const s16x8*)&lds[VT + n16 * 264 + ch * 32 + quad * 8];
        #pragma unroll
        for (int qt = 0; qt < 4; ++qt) {
            f32x4 zc = {};
            f32x4 s0 = MFMA16(kf0, qa[qt], zc);      // S^T: col=i(n16), row=j-local
            float e0 = exp2f(s0[0]), e1 = exp2f(s0[1]);
            float e2 = exp2f(s0[2]), e3 = exp2f(s0[3]);
            lrow[qt][0] += e0; lrow[qt][1] += e1;
            lrow[qt][2] += e2; lrow[qt][3] += e3;
            uint2 p0 = {pk2(e0, e1), pk2(e2, e3)};
            *(uint2*)&scr[n16 * 40 + quad * 4] = p0;          // j = quad*4..+4
            f32x4 s1 = MFMA16(kf1, qa[qt], zc);
            float f0 = exp2f(s1[0]), f1 = exp2f(s1[1]);
            float f2 = exp2f(s1[2]), f3 = exp2f(s1[3]);
            lrow[qt][0] += f0; lrow[qt][1] += f1;
            lrow[qt][2] += f2; lrow[qt][3] += f3;
            uint2 p1 = {pk2(f0, f1), pk2(f2, f3)};
            *(uint2*)&scr[n16 * 40 + 16 + quad * 4] = p1;     // j = 16 + quad*4..+4
            // P^T B-frag: thread (n16,quad) -> P[i=n16][j=quad*8..+8]
            s16x8 pf = *(const s16x8*)&scr[n16 * 40 + quad * 8];
            o4[qt] = MFMA16(vf, pf, o4[qt]);         // O^T: col=i, row=dh
        }
    }

    // ---- epilogue: l-reduce, gate, coalesced GO stores ----
    #pragma unroll
    for (int qt = 0; qt < 4; ++qt) {
        float l = lrow[qt][0] + lrow[qt][1] + lrow[qt][2] + lrow[qt][3];
        l += __shfl_xor(l, 16);
        l += __shfl_xor(l, 32);
        const float inv = 1.f / l;
        float g0 = g4t[qt][0] * o4[qt][0] * inv;
        float g1 = g4t[qt][1] * o4[qt][1] * inv;
        float g2 = g4t[qt][2] * o4[qt][2] * inv;
        float g3 = g4t[qt][3] * o4[qt][3] * inv;
        uint2 p = {pk2(g0, g1), pk2(g2, g3)};
        short* dst = go + (((size_t)h * 512 + bl) * 256 + w * 64 + qt * 16 + n16) * 16
                     + quad * 4;
        *(uint2*)dst = p;
    }
}

// ---------------------------------------------------------------- kernel 3
// out = sum_h GO_h @ Wo_h^T + bo ; grid 1024 (bl,half), block 256, 32 rows/wave
__global__ __launch_bounds__(256, 4)
void k3_out(const short* __restrict__ go, const float* __restrict__ Wo,
            const float* __restrict__ bo, float* __restrict__ out)
{
    const int tid = threadIdx.x, lane = tid & 63, w = tid >> 6;
    const int n16 = lane & 15, quad = lane >> 4;
    const int bl = blockIdx.x >> 1, half = blockIdx.x & 1;
    const int rowloc = half * 128 + w * 32;

    s16x8 bfr[4][2];   // B[k=ch][n=outd] = Wo[outd][ch]
    #pragma unroll
    for (int nt = 0; nt < 4; ++nt)
        #pragma unroll
        for (int ks = 0; ks < 2; ++ks)
            bfr[nt][ks] = cvt8(Wo + (size_t)(nt * 16 + n16) * 64 + ks * 32 + quad * 8);

    f32x4 acc[2][4] = {};
    #pragma unroll
    for (int mt = 0; mt < 2; ++mt) {
        #pragma unroll
        for (int c = 0; c < 2; ++c) {
            int hp = c * 2 + (quad >> 1);
            const short* ap = &go[(((size_t)hp * 512 + bl) * 256 + rowloc + mt * 16 + n16) * 16
                                  + (quad & 1) * 8];
            s16x8 a = *(const s16x8*)ap;
            #pragma unroll
            for (int nt = 0; nt < 4; ++nt)
                acc[mt][nt] = MFMA16(a, bfr[nt][c], acc[mt][nt]);
        }
    }
    #pragma unroll
    for (int nt = 0; nt < 4; ++nt) {
        float bov = bo[nt * 16 + n16];
        #pragma unroll
        for (int mt = 0; mt < 2; ++mt)
            #pragma unroll
            for (int r = 0; r < 4; ++r)
                out[((size_t)bl * 256 + rowloc + mt * 16 + quad * 4 + r) * 64 + nt * 16 + n16] =
                    acc[mt][nt][r] + bov;
    }
}

extern "C" void kernel_launch(void* const* d_in, const int* in_sizes, int n_in,
                              void* d_out, int out_size, void* d_ws, size_t ws_size,
                              hipStream_t stream) {
    const float* z  = (const float*)d_in[0];
    const float* ls = (const float*)d_in[1];
    const float* lb = (const float*)d_in[2];
    const float* Wq = (const float*)d_in[3];
    const float* Wk = (const float*)d_in[4];
    const float* Wv = (const float*)d_in[5];
    const float* Wg = (const float*)d_in[6];
    const float* bg = (const float*)d_in[7];
    const float* Wo = (const float*)d_in[8];
    const float* bo = (const float*)d_in[9];
    float* out = (float*)d_out;
    short* wsp = (short*)d_ws;

    hipLaunchKernelGGL(kln, dim3(512), dim3(256), 0, stream, z, ls, lb, wsp + ZNOFF);
    hipLaunchKernelGGL(ka_fused, dim3(2048), dim3(256), 0, stream,
                       wsp + ZNOFF, Wq, Wk, Wv, Wg, bg, wsp + GOOFF);
    hipLaunchKernelGGL(k3_out, dim3(1024), dim3(256), 0, stream, wsp + GOOFF, Wo, bo, out);
}

// Round 8
// 269.929 us; speedup vs baseline: 1.3904x; 1.3904x over previous
//
#include <hip/hip_runtime.h>
#include <hip/hip_bf16.h>
#include <math.h>

// TriangleAttention — round 8: round-7 structure, launch_bounds fixed (5->4)
// to eliminate scratch spills (r7: VGPR forced to 48 -> 640 MB spill traffic).
// B=2, L=256, D=64, H=4, Dh=16.
// kln: LN once -> zn bf16 [bl*256+pos][64] in ws.
// ka:  grid 2048=(bl,h); S^T formulation, zn frags direct from global,
//      LDS ~25KB, one barrier, 4 blocks/CU (16 waves).
// k3:  out = sum_h GO_h @ Wo_h^T + bo.
//
// mfma_f32_16x16x32_bf16 layouts (verified rounds 2-6):
//   A[m = lane&15][k = quad*8 + u]
//   B[k = quad*8 + u][n = lane&15]
//   C/D: col = lane&15, row = quad*4 + reg

typedef __attribute__((ext_vector_type(4))) float f32x4;
typedef __attribute__((ext_vector_type(8))) short s16x8;

#define MFMA16(a, b, c) __builtin_amdgcn_mfma_f32_16x16x32_bf16((a), (b), (c), 0, 0, 0)

__device__ __forceinline__ unsigned pk2(float a, float b) {   // 2xf32 -> packed bf16x2 (RNE)
    union { __hip_bfloat162 h; unsigned u; } c;
    float2 t; t.x = a; t.y = b;
    c.h = __float22bfloat162_rn(t);
    return c.u;
}
__device__ __forceinline__ s16x8 cvt8(const float* p) {  // 8 fp32 -> bf16x8
    union { unsigned u[4]; s16x8 v; } r;
    r.u[0] = pk2(p[0], p[1]); r.u[1] = pk2(p[2], p[3]);
    r.u[2] = pk2(p[4], p[5]); r.u[3] = pk2(p[6], p[7]);
    return r.v;
}

// ws layout (shorts)
static constexpr size_t ZNOFF = 0;                        // zn bf16 [131072 rows][64]
static constexpr size_t GOOFF = (size_t)512 * 256 * 64;   // GO [h][bl][pos][16]

// ---------------------------------------------------------------- LN kernel
__global__ __launch_bounds__(256, 2)
void kln(const float* __restrict__ z, const float* __restrict__ ln_s,
         const float* __restrict__ ln_b, short* __restrict__ ws)
{
    const int tid = threadIdx.x, bl = blockIdx.x;
    const size_t row = (size_t)bl * 256 + tid;
    float zn[64];
    const float4* zp4 = (const float4*)(z + row * 64);
    #pragma unroll
    for (int gq = 0; gq < 16; ++gq) {
        float4 v4 = zp4[gq];
        zn[gq * 4 + 0] = v4.x; zn[gq * 4 + 1] = v4.y;
        zn[gq * 4 + 2] = v4.z; zn[gq * 4 + 3] = v4.w;
    }
    float mu = 0.f;
    #pragma unroll
    for (int k = 0; k < 64; ++k) mu += zn[k];
    mu *= (1.f / 64.f);
    float va = 0.f;
    #pragma unroll
    for (int k = 0; k < 64; ++k) { float d = zn[k] - mu; va += d * d; }
    const float rs = rsqrtf(va * (1.f / 64.f) + 1e-5f);
    #pragma unroll
    for (int k = 0; k < 64; ++k) zn[k] = (zn[k] - mu) * rs * ln_s[k] + ln_b[k];
    short* dst = ws + ZNOFF + row * 64;
    #pragma unroll
    for (int gq = 0; gq < 8; ++gq) {
        union { unsigned u[4]; s16x8 v; } pkv;
        pkv.u[0] = pk2(zn[gq * 8 + 0], zn[gq * 8 + 1]);
        pkv.u[1] = pk2(zn[gq * 8 + 2], zn[gq * 8 + 3]);
        pkv.u[2] = pk2(zn[gq * 8 + 4], zn[gq * 8 + 5]);
        pkv.u[3] = pk2(zn[gq * 8 + 6], zn[gq * 8 + 7]);
        *(s16x8*)&dst[gq * 8] = pkv.v;
    }
}

// ---------------------------------------------------------------- fused attention
// LDS map (shorts): KSH [256 pos][24-stride, dh in first 16]; VT [16 dh][264];
// SCR per-wave 640 sh: QT tile [pos16][16] then P [i16][40-stride].
static constexpr int KSH = 0;            // 6144 sh
static constexpr int VT  = 6144;         // 4224 sh
static constexpr int SCR = 10368;        // 4 x 640 sh
static constexpr int LDS_EL = 12928;     // 25856 B

__global__ __launch_bounds__(256, 4)   // r7 had 5 -> spills; 4 gives 128-VGPR budget
void ka_fused(const short* __restrict__ zng, const float* __restrict__ Wq,
              const float* __restrict__ Wk, const float* __restrict__ Wv,
              const float* __restrict__ Wg, const float* __restrict__ bg,
              short* __restrict__ go)
{
    __shared__ __align__(16) short lds[LDS_EL];
    const int tid = threadIdx.x, lane = tid & 63, w = tid >> 6;
    const int n16 = lane & 15, quad = lane >> 4;
    const bool qlo = (quad < 2);
    const int g = blockIdx.x, bl = g >> 2, h = g & 3;
    short* scr = &lds[SCR + w * 640];

    // ---- zn fragments direct from global (coalesced b128) ----
    s16x8 zf[4][2];
    const short* zb = zng + ((size_t)bl * 256 + w * 64 + n16) * 64;
    #pragma unroll
    for (int t = 0; t < 4; ++t) {
        zf[t][0] = *(const s16x8*)&zb[t * 1024 + quad * 8];
        zf[t][1] = *(const s16x8*)&zb[t * 1024 + 32 + quad * 8];
    }

    // ---- W head-slice frags ----
    s16x8 bq[2], bk[2], bv[2], bgf[2];
    #pragma unroll
    for (int ks = 0; ks < 2; ++ks) {
        size_t off = (size_t)(h * 16 + n16) * 64 + ks * 32 + quad * 8;
        bq[ks] = cvt8(Wq + off);  bk[ks] = cvt8(Wk + off);
        bv[ks] = cvt8(Wv + off);  bgf[ks] = cvt8(Wg + off);
    }
    const float4 bg4 = *(const float4*)(bg + h * 16 + quad * 4);
    constexpr float QS = 0.25f * 1.44269504088896340736f;   // 1/sqrt(Dh) * log2(e)

    // ---- projections; Q^T via tiny wave-private LDS transpose ----
    float g4t[4][4];
    s16x8 qa[4];
    #pragma unroll
    for (int t = 0; t < 4; ++t) {
        f32x4 aq = {}, ak = {}, av = {}, ag = {};
        aq = MFMA16(bq[0],  zf[t][0], aq); aq = MFMA16(bq[1],  zf[t][1], aq);  // Q^T
        ak = MFMA16(bk[0],  zf[t][0], ak); ak = MFMA16(bk[1],  zf[t][1], ak);  // K^T
        ag = MFMA16(bgf[0], zf[t][0], ag); ag = MFMA16(bgf[1], zf[t][1], ag);  // G^T
        av = MFMA16(zf[t][0], bv[0], av);  av = MFMA16(zf[t][1], bv[1], av);   // V
        {   // Q^T -> scr QT [pos16][16] (scaled), then read back as B-frag
            uint2 p = {pk2(aq[0] * QS, aq[1] * QS), pk2(aq[2] * QS, aq[3] * QS)};
            *(uint2*)&scr[n16 * 16 + quad * 4] = p;
        }
        {   // K^T -> KSH[pos][dh], stride 24
            uint2 p = {pk2(ak[0], ak[1]), pk2(ak[2], ak[3])};
            *(uint2*)&lds[KSH + (w * 64 + t * 16 + n16) * 24 + quad * 4] = p;
        }
        {   // V -> VT[dh][pos]
            uint2 p = {pk2(av[0], av[1]), pk2(av[2], av[3])};
            *(uint2*)&lds[VT + n16 * 264 + (w * 64 + t * 16 + quad * 4)] = p;
        }
        #pragma unroll
        for (int r = 0; r < 4; ++r)
            g4t[t][r] = 1.f / (1.f + __expf(-(ag[r] + bg4[r])));
        // Q^T B-frag (wave-private, in-order DS; quads 2,3 zero: Dh=16 < K=32)
        s16x8 q = {};
        if (qlo) q = *(const s16x8*)&scr[n16 * 16 + quad * 8];
        qa[t] = q;
    }
    __syncthreads();   // the ONLY barrier: KSH/VT visible

    // ---- attention: S^T = K@Q^T; P packed [i][j] in scr; O^T = V^T@P^T ----
    float lrow[4][4];
    f32x4 o4[4];
    #pragma unroll
    for (int qt = 0; qt < 4; ++qt) {
        o4[qt] = {};
        #pragma unroll
        for (int r = 0; r < 4; ++r) lrow[qt][r] = 0.f;
    }
    for (int ch = 0; ch < 8; ++ch) {                 // 32 keys per chunk
        s16x8 kf0 = {}, kf1 = {};
        if (qlo) {
            kf0 = *(const s16x8*)&lds[KSH + ((ch * 2 + 0) * 16 + n16) * 24 + quad * 8];
            kf1 = *(const s16x8*)&lds[KSH + ((ch * 2 + 1) * 16 + n16) * 24 + quad * 8];
        }
        s16x8 vf = *(const s16x8*)&lds[VT + n16 * 264 + ch * 32 + quad * 8];
        #pragma unroll
        for (int qt = 0; qt < 4; ++qt) {
            f32x4 zc = {};
            f32x4 s0 = MFMA16(kf0, qa[qt], zc);      // S^T: col=i(n16), row=j-local
            float e0 = exp2f(s0[0]), e1 = exp2f(s0[1]);
            float e2 = exp2f(s0[2]), e3 = exp2f(s0[3]);
            lrow[qt][0] += e0; lrow[qt][1] += e1;
            lrow[qt][2] += e2; lrow[qt][3] += e3;
            uint2 p0 = {pk2(e0, e1), pk2(e2, e3)};
            *(uint2*)&scr[n16 * 40 + quad * 4] = p0;          // j = quad*4..+4
            f32x4 s1 = MFMA16(kf1, qa[qt], zc);
            float f0 = exp2f(s1[0]), f1 = exp2f(s1[1]);
            float f2 = exp2f(s1[2]), f3 = exp2f(s1[3]);
            lrow[qt][0] += f0; lrow[qt][1] += f1;
            lrow[qt][2] += f2; lrow[qt][3] += f3;
            uint2 p1 = {pk2(f0, f1), pk2(f2, f3)};
            *(uint2*)&scr[n16 * 40 + 16 + quad * 4] = p1;     // j = 16 + quad*4..+4
            // P^T B-frag: thread (n16,quad) -> P[i=n16][j=quad*8..+8]
            s16x8 pf = *(const s16x8*)&scr[n16 * 40 + quad * 8];
            o4[qt] = MFMA16(vf, pf, o4[qt]);         // O^T: col=i, row=dh
        }
    }

    // ---- epilogue: l-reduce, gate, coalesced GO stores ----
    #pragma unroll
    for (int qt = 0; qt < 4; ++qt) {
        float l = lrow[qt][0] + lrow[qt][1] + lrow[qt][2] + lrow[qt][3];
        l += __shfl_xor(l, 16);
        l += __shfl_xor(l, 32);
        const float inv = 1.f / l;
        float g0 = g4t[qt][0] * o4[qt][0] * inv;
        float g1 = g4t[qt][1] * o4[qt][1] * inv;
        float g2 = g4t[qt][2] * o4[qt][2] * inv;
        float g3 = g4t[qt][3] * o4[qt][3] * inv;
        uint2 p = {pk2(g0, g1), pk2(g2, g3)};
        short* dst = go + (((size_t)h * 512 + bl) * 256 + w * 64 + qt * 16 + n16) * 16
                     + quad * 4;
        *(uint2*)dst = p;
    }
}

// ---------------------------------------------------------------- kernel 3
// out = sum_h GO_h @ Wo_h^T + bo ; grid 1024 (bl,half), block 256, 32 rows/wave
__global__ __launch_bounds__(256, 4)
void k3_out(const short* __restrict__ go, const float* __restrict__ Wo,
            const float* __restrict__ bo, float* __restrict__ out)
{
    const int tid = threadIdx.x, lane = tid & 63, w = tid >> 6;
    const int n16 = lane & 15, quad = lane >> 4;
    const int bl = blockIdx.x >> 1, half = blockIdx.x & 1;
    const int rowloc = half * 128 + w * 32;

    s16x8 bfr[4][2];   // B[k=ch][n=outd] = Wo[outd][ch]
    #pragma unroll
    for (int nt = 0; nt < 4; ++nt)
        #pragma unroll
        for (int ks = 0; ks < 2; ++ks)
            bfr[nt][ks] = cvt8(Wo + (size_t)(nt * 16 + n16) * 64 + ks * 32 + quad * 8);

    f32x4 acc[2][4] = {};
    #pragma unroll
    for (int mt = 0; mt < 2; ++mt) {
        #pragma unroll
        for (int c = 0; c < 2; ++c) {
            int hp = c * 2 + (quad >> 1);
            const short* ap = &go[(((size_t)hp * 512 + bl) * 256 + rowloc + mt * 16 + n16) * 16
                                  + (quad & 1) * 8];
            s16x8 a = *(const s16x8*)ap;
            #pragma unroll
            for (int nt = 0; nt < 4; ++nt)
                acc[mt][nt] = MFMA16(a, bfr[nt][c], acc[mt][nt]);
        }
    }
    #pragma unroll
    for (int nt = 0; nt < 4; ++nt) {
        float bov = bo[nt * 16 + n16];
        #pragma unroll
        for (int mt = 0; mt < 2; ++mt)
            #pragma unroll
            for (int r = 0; r < 4; ++r)
                out[((size_t)bl * 256 + rowloc + mt * 16 + quad * 4 + r) * 64 + nt * 16 + n16] =
                    acc[mt][nt][r] + bov;
    }
}

extern "C" void kernel_launch(void* const* d_in, const int* in_sizes, int n_in,
                              void* d_out, int out_size, void* d_ws, size_t ws_size,
                              hipStream_t stream) {
    const float* z  = (const float*)d_in[0];
    const float* ls = (const float*)d_in[1];
    const float* lb = (const float*)d_in[2];
    const float* Wq = (const float*)d_in[3];
    const float* Wk = (const float*)d_in[4];
    const float* Wv = (const float*)d_in[5];
    const float* Wg = (const float*)d_in[6];
    const float* bg = (const float*)d_in[7];
    const float* Wo = (const float*)d_in[8];
    const float* bo = (const float*)d_in[9];
    float* out = (float*)d_out;
    short* wsp = (short*)d_ws;

    hipLaunchKernelGGL(kln, dim3(512), dim3(256), 0, stream, z, ls, lb, wsp + ZNOFF);
    hipLaunchKernelGGL(ka_fused, dim3(2048), dim3(256), 0, stream,
                       wsp + ZNOFF, Wq, Wk, Wv, Wg, bg, wsp + GOOFF);
    hipLaunchKernelGGL(k3_out, dim3(1024), dim3(256), 0, stream, wsp + GOOFF, Wo, bo, out);
}